// Round 1
// baseline (1155.724 us; speedup 1.0000x reference)
//
#include <hip/hip_runtime.h>

// SAMMCodebook.encode: z[n] = argmin_k ||h_n - c_k||^2
//   = argmin_k ( c_sq[k] - 2 <h_n, c_k> )   (h_sq is row-constant)
//
// h: [65536, 1024] fp32, codebook: [512, 1024] fp32, out: [65536] int32.
//
// Round 1: fp32 vector baseline. Compute-bound: 34.4 G-FMA -> 437 us floor
// at 157 TF. 128x128x64 LDS-tiled register GEMM with running argmin.

#define D_DIM   1024
#define K_CB    512

#define BM      128   // rows per block
#define BN      128   // codewords per chunk (4 chunks cover K=512)
#define BK      64    // d per LDS stage
#define LDS_PAD 4     // keeps row stride 132 floats = 33*16B (b128-aligned)
#define TM      8     // rows per thread (two groups of 4: ty*4, 64+ty*4)
#define TN      8     // cols per thread (two groups of 4: tx*4, 64+tx*4)

__global__ void csq_kernel(const float* __restrict__ cb, float* __restrict__ csq) {
    // one wave per codeword; 256 threads = 4 waves/block, 128 blocks
    const int wave = threadIdx.x >> 6;
    const int lane = threadIdx.x & 63;
    const int k = blockIdx.x * 4 + wave;
    if (k >= K_CB) return;
    const float* row = cb + (size_t)k * D_DIM;
    float s = 0.0f;
    #pragma unroll
    for (int i = 0; i < D_DIM / 64; ++i) {
        const float v = row[i * 64 + lane];   // coalesced
        s = fmaf(v, v, s);
    }
    #pragma unroll
    for (int off = 32; off > 0; off >>= 1)
        s += __shfl_down(s, off, 64);
    if (lane == 0) csq[k] = s;
}

__global__ __launch_bounds__(256, 2)
void encode_kernel(const float* __restrict__ h,
                   const float* __restrict__ cb,
                   const float* __restrict__ csq,
                   int* __restrict__ out) {
    // Transposed tiles: [d][row] so the inner loop reads contiguous rows/cols
    // per fixed d with ds_read_b128. Stride 132 floats (16B-aligned).
    __shared__ float hs[BK][BM + LDS_PAD];
    __shared__ float cs[BK][BN + LDS_PAD];

    const int tid = threadIdx.x;
    const int tx = tid & 15;
    const int ty = tid >> 4;
    const size_t row0 = (size_t)blockIdx.x * BM;

    float bestv[TM];
    int   besti[TM];
    #pragma unroll
    for (int i = 0; i < TM; ++i) { bestv[i] = 3.4e38f; besti[i] = 0; }

    const int dq = tx * 4;   // this thread's 4-wide d slot within the BK chunk

    for (int cc = 0; cc < K_CB; cc += BN) {
        float acc[TM][TN];
        #pragma unroll
        for (int i = 0; i < TM; ++i)
            #pragma unroll
            for (int j = 0; j < TN; ++j) acc[i][j] = 0.0f;

        for (int dk = 0; dk < D_DIM; dk += BK) {
            // Stage h[128 x 64] and cb[128 x 64] transposed into LDS.
            // Lane tx sweeps d (coalesced float4), r covers 0..127 over 8 passes.
            #pragma unroll
            for (int p = 0; p < 8; ++p) {
                const int r = ty + 16 * p;
                const float4 v = *(const float4*)(h + (row0 + r) * D_DIM + dk + dq);
                hs[dq + 0][r] = v.x; hs[dq + 1][r] = v.y;
                hs[dq + 2][r] = v.z; hs[dq + 3][r] = v.w;
                const float4 w = *(const float4*)(cb + (size_t)(cc + r) * D_DIM + dk + dq);
                cs[dq + 0][r] = w.x; cs[dq + 1][r] = w.y;
                cs[dq + 2][r] = w.z; cs[dq + 3][r] = w.w;
            }
            __syncthreads();

            #pragma unroll 8
            for (int d = 0; d < BK; ++d) {
                float hv[TM], cv[TN];
                // two b128 per operand; 64-float sweeps -> <=2-way bank alias (free)
                *(float4*)&hv[0] = *(const float4*)&hs[d][ty * 4];
                *(float4*)&hv[4] = *(const float4*)&hs[d][64 + ty * 4];
                *(float4*)&cv[0] = *(const float4*)&cs[d][tx * 4];
                *(float4*)&cv[4] = *(const float4*)&cs[d][64 + tx * 4];
                #pragma unroll
                for (int i = 0; i < TM; ++i)
                    #pragma unroll
                    for (int j = 0; j < TN; ++j)
                        acc[i][j] = fmaf(hv[i], cv[j], acc[i][j]);
            }
            __syncthreads();
        }

        // score = c_sq - 2*dot; update running argmin with first-index tie rule
        #pragma unroll
        for (int j = 0; j < TN; ++j) {
            const int c = cc + ((j < 4) ? (tx * 4 + j) : (64 + tx * 4 + (j - 4)));
            const float c2 = csq[c];
            #pragma unroll
            for (int i = 0; i < TM; ++i) {
                const float s = fmaf(-2.0f, acc[i][j], c2);
                if (s < bestv[i] || (s == bestv[i] && c < besti[i])) {
                    bestv[i] = s; besti[i] = c;
                }
            }
        }
    }

    // Cross-thread merge: 16 candidates per row (one per tx), via reused LDS.
    __syncthreads();
    float* mv = &hs[0][0];
    int*   mi = (int*)&cs[0][0];
    #pragma unroll
    for (int i = 0; i < TM; ++i) {
        const int r = (i < 4) ? (ty * 4 + i) : (64 + ty * 4 + (i - 4));
        mv[r * 16 + tx] = bestv[i];
        mi[r * 16 + tx] = besti[i];
    }
    __syncthreads();
    if (tid < BM) {
        float bv = mv[tid * 16];
        int   bi = mi[tid * 16];
        #pragma unroll
        for (int t = 1; t < 16; ++t) {
            const float v = mv[tid * 16 + t];
            const int  ix = mi[tid * 16 + t];
            if (v < bv || (v == bv && ix < bi)) { bv = v; bi = ix; }
        }
        out[row0 + tid] = bi;
    }
}

extern "C" void kernel_launch(void* const* d_in, const int* in_sizes, int n_in,
                              void* d_out, int out_size, void* d_ws, size_t ws_size,
                              hipStream_t stream) {
    const float* h  = (const float*)d_in[0];
    const float* cb = (const float*)d_in[1];
    int*   out = (int*)d_out;
    float* csq = (float*)d_ws;   // 512 floats of scratch

    const int nrows = in_sizes[0] / D_DIM;   // 65536

    csq_kernel<<<dim3(K_CB / 4), dim3(256), 0, stream>>>(cb, csq);
    encode_kernel<<<dim3(nrows / BM), dim3(256), 0, stream>>>(h, cb, csq, out);
}

// Round 2
// 486.063 us; speedup vs baseline: 2.3777x; 2.3777x over previous
//
#include <hip/hip_runtime.h>

// SAMMCodebook.encode, round 2: bf16-MFMA coarse scoring + exact fp32 refine.
//
// z[n] = argmin_k (csq[k] - 2<h_n,c_k>)  (h_sq row-constant, dropped).
// Coarse: s~ = csq - 2*dot_bf16 (MFMA 16x16x32, fp32 accum). Error std ~0.11;
// margin DELTA=4.0 (~36 sigma) guarantees the true argmin is among candidates.
// Refine: exact fp32 scoring of the (typically 1-3) candidates per row.
//
// d_ws layout: [0,1MB) cb_bf16; [1MB,+2KB) csq f32; then 16B slot per
// (row,half): {f32 bestval, u16 bestcol, u16 cnt, u16 cd[4]} -> ~3.1 MB total.

#define D_DIM 1024
#define K_CB  512
#define BM    64      // rows per block
#define BN    256     // cols per block (2 halves cover K=512)
#define BK    64
#define STRIDE 72     // BK + 8 bf16 pad: 144B row stride, uniform bank spread
#define DELTA 4.0f
#define SENTINEL 0x7FFF

typedef __attribute__((ext_vector_type(8))) short short8;
typedef __attribute__((ext_vector_type(4))) float floatx4;

static __device__ __forceinline__ unsigned short f2bf(float f) {
    unsigned u = __builtin_bit_cast(unsigned, f);
    unsigned r = (u + 0x7FFFu + ((u >> 16) & 1u)) >> 16;   // round-nearest-even
    return (unsigned short)r;
}

// ---------------- prep: cb fp32 -> bf16, csq ----------------
__global__ __launch_bounds__(256)
void prep_kernel(const float* __restrict__ cb, unsigned short* __restrict__ cbb,
                 float* __restrict__ csq) {
    __shared__ float red[4];
    const int k = blockIdx.x, t = threadIdx.x;
    const float4 v = *(const float4*)(cb + (size_t)k * D_DIM + t * 4);
    uint2 u;
    u.x = (unsigned)f2bf(v.x) | ((unsigned)f2bf(v.y) << 16);
    u.y = (unsigned)f2bf(v.z) | ((unsigned)f2bf(v.w) << 16);
    *(uint2*)(cbb + (size_t)k * D_DIM + t * 4) = u;
    float s = v.x * v.x + v.y * v.y + v.z * v.z + v.w * v.w;
    #pragma unroll
    for (int off = 32; off > 0; off >>= 1) s += __shfl_down(s, off, 64);
    if ((t & 63) == 0) red[t >> 6] = s;
    __syncthreads();
    if (t == 0) csq[k] = red[0] + red[1] + red[2] + red[3];
}

// ---------------- coarse: MFMA scores + per-row candidate slots ----------------
__global__ __launch_bounds__(256)
void coarse_kernel(const float* __restrict__ h,
                   const unsigned short* __restrict__ cbb,
                   const float* __restrict__ csq,
                   uint4* __restrict__ slots) {
    __shared__ unsigned char smem[46080] __attribute__((aligned(16)));
    unsigned short* hs = (unsigned short*)smem;                      // [64][72]
    unsigned short* cs = (unsigned short*)(smem + 64 * STRIDE * 2);  // [256][72]

    const int tid = threadIdx.x;
    const int w = tid >> 6;
    const int lane = tid & 63;
    const int l15 = lane & 15;
    const int kq = lane >> 4;

    const int rowblk = blockIdx.x >> 1;
    const int half = blockIdx.x & 1;             // adjacent bx pair shares h rows
    const size_t row0 = (size_t)rowblk * BM;
    const int col0 = half * BN;

    const int wr = (w >> 1) * 32;                // wave row offset in block
    const int wc = (w & 1) * 128;                // wave col offset in block

    floatx4 acc[2][8];
    #pragma unroll
    for (int i = 0; i < 2; ++i)
        #pragma unroll
        for (int j = 0; j < 8; ++j) acc[i][j] = (floatx4){0.f, 0.f, 0.f, 0.f};

    for (int dk = 0; dk < D_DIM; dk += BK) {
        // stage h (64x64 fp32 -> bf16)
        #pragma unroll
        for (int p = 0; p < 4; ++p) {
            const int f = p * 256 + tid;         // 0..1023
            const int r = f >> 4, c4 = f & 15;
            const float4 v = *(const float4*)(h + (row0 + r) * D_DIM + dk + c4 * 4);
            uint2 u;
            u.x = (unsigned)f2bf(v.x) | ((unsigned)f2bf(v.y) << 16);
            u.y = (unsigned)f2bf(v.z) | ((unsigned)f2bf(v.w) << 16);
            *(uint2*)(hs + r * STRIDE + c4 * 4) = u;
        }
        // stage cb bf16 (256x64)
        #pragma unroll
        for (int p = 0; p < 8; ++p) {
            const int f = p * 256 + tid;         // 0..2047
            const int cr = f >> 3, g = f & 7;
            const uint4 u = *(const uint4*)(cbb + (size_t)(col0 + cr) * D_DIM + dk + g * 8);
            *(uint4*)(cs + cr * STRIDE + g * 8) = u;
        }
        __syncthreads();
        #pragma unroll
        for (int ks = 0; ks < BK; ks += 32) {
            short8 a[2], b[8];
            #pragma unroll
            for (int rt = 0; rt < 2; ++rt)
                a[rt] = *(const short8*)(hs + (wr + rt * 16 + l15) * STRIDE + ks + kq * 8);
            #pragma unroll
            for (int ct = 0; ct < 8; ++ct)
                b[ct] = *(const short8*)(cs + (wc + ct * 16 + l15) * STRIDE + ks + kq * 8);
            #pragma unroll
            for (int rt = 0; rt < 2; ++rt)
                #pragma unroll
                for (int ct = 0; ct < 8; ++ct)
                    acc[rt][ct] = __builtin_amdgcn_mfma_f32_16x16x32_bf16(
                        a[rt], b[ct], acc[rt][ct], 0, 0, 0);
        }
        __syncthreads();
    }

    // per-lane top-2 over the 8 cols each (lane,row) holds
    float k1[8], k2[8];
    int   c1[8], c2[8];
    #pragma unroll
    for (int i = 0; i < 8; ++i) { k1[i] = 3.4e38f; k2[i] = 3.4e38f; c1[i] = 0; c2[i] = 0; }

    #pragma unroll
    for (int ct = 0; ct < 8; ++ct) {
        const int col = col0 + wc + ct * 16 + l15;
        const float cq = csq[col];
        #pragma unroll
        for (int rt = 0; rt < 2; ++rt)
            #pragma unroll
            for (int reg = 0; reg < 4; ++reg) {
                const float s = fmaf(-2.0f, acc[rt][ct][reg], cq);
                const int ri = rt * 4 + reg;
                if (s < k1[ri]) { k2[ri] = k1[ri]; c2[ri] = c1[ri]; k1[ri] = s; c1[ri] = col; }
                else if (s < k2[ri]) { k2[ri] = s; c2[ri] = col; }
            }
    }

    // merge via LDS: per row 64 entries (32 cells x top2)
    float* mval = (float*)smem;                       // [64][66]
    int*   mcol = (int*)(smem + 64 * 66 * 4);         // [64][66]
    __syncthreads();
    #pragma unroll
    for (int rt = 0; rt < 2; ++rt)
        #pragma unroll
        for (int reg = 0; reg < 4; ++reg) {
            const int ri = rt * 4 + reg;
            const int r = wr + rt * 16 + kq * 4 + reg;
            const int e = ((w & 1) * 16 + l15) * 2;
            mval[r * 66 + e] = k1[ri];     mcol[r * 66 + e] = c1[ri];
            mval[r * 66 + e + 1] = k2[ri]; mcol[r * 66 + e + 1] = c2[ri];
        }
    __syncthreads();

    if (tid < 64) {
        const int r = tid;
        float bv = 3.4e38f; int bc = 0x7fffffff;
        for (int e = 0; e < 64; ++e) {
            const float v = mval[r * 66 + e];
            const int   c = mcol[r * 66 + e];
            if (v < bv || (v == bv && c < bc)) { bv = v; bc = c; }
        }
        const float thr = bv + DELTA;
        unsigned cd[4] = {0, 0, 0, 0};
        int others = 0;
        for (int e = 0; e < 64; ++e) {
            const float v = mval[r * 66 + e];
            const int   c = mcol[r * 66 + e];
            if (v < thr && c != bc) {
                if (others < 4) cd[others] = (unsigned)c;
                ++others;
            }
        }
        unsigned cnt = (others > 4) ? (unsigned)SENTINEL : (unsigned)(1 + others);
        uint4 s;
        s.x = __builtin_bit_cast(unsigned, bv);
        s.y = (unsigned)bc | (cnt << 16);
        s.z = cd[0] | (cd[1] << 16);
        s.w = cd[2] | (cd[3] << 16);
        slots[(row0 + r) * 2 + half] = s;
    }
}

// ---------------- refine: exact fp32 on candidates ----------------
__global__ __launch_bounds__(256)
void refine_kernel(const float* __restrict__ h, const float* __restrict__ cb,
                   const float* __restrict__ csq, const uint4* __restrict__ slots,
                   int* __restrict__ out) {
    const int w = threadIdx.x >> 6;
    const int lane = threadIdx.x & 63;
    const size_t row = (size_t)blockIdx.x * 4 + w;

    const uint4 s0 = slots[row * 2 + 0];
    const uint4 s1 = slots[row * 2 + 1];
    const float bv0 = __builtin_bit_cast(float, s0.x);
    const float bv1 = __builtin_bit_cast(float, s1.x);
    const float gmin = fminf(bv0, bv1);
    const float thr = gmin + DELTA;

    int cl[10];
    int nc = 0;
    bool full = false;
    {
        const uint4 ss[2] = {s0, s1};
        const float bvh[2] = {bv0, bv1};
        for (int hh = 0; hh < 2; ++hh) {
            if (!(bvh[hh] < thr)) continue;
            const unsigned cnt = ss[hh].y >> 16;
            if (cnt == SENTINEL) { full = true; continue; }
            cl[nc++] = (int)(ss[hh].y & 0xFFFFu);          // best first
            const unsigned cds[4] = {ss[hh].z & 0xFFFFu, ss[hh].z >> 16,
                                     ss[hh].w & 0xFFFFu, ss[hh].w >> 16};
            for (unsigned i = 0; i + 1 < cnt; ++i) cl[nc++] = (int)cds[i];
        }
    }

    if (!full && nc == 1) {               // unambiguous: approx winner is exact
        if (lane == 0) out[row] = cl[0];
        return;
    }

    const float* hrow = h + row * D_DIM;
    float4 hv[4];
    #pragma unroll
    for (int j = 0; j < 4; ++j)
        hv[j] = *(const float4*)(hrow + j * 256 + lane * 4);

    float bs = 3.4e38f; int bc = 0x7fffffff;
    const int total = full ? K_CB : nc;
    for (int i = 0; i < total; ++i) {
        const int c = full ? i : cl[i];
        const float* crow = cb + (size_t)c * D_DIM;
        float d = 0.0f;
        #pragma unroll
        for (int j = 0; j < 4; ++j) {
            const float4 cv = *(const float4*)(crow + j * 256 + lane * 4);
            d = fmaf(hv[j].x, cv.x, d);
            d = fmaf(hv[j].y, cv.y, d);
            d = fmaf(hv[j].z, cv.z, d);
            d = fmaf(hv[j].w, cv.w, d);
        }
        #pragma unroll
        for (int off = 32; off > 0; off >>= 1) d += __shfl_down(d, off, 64);
        d = __shfl(d, 0, 64);
        const float s = fmaf(-2.0f, d, csq[c]);
        if (s < bs || (s == bs && c < bc)) { bs = s; bc = c; }
    }
    if (lane == 0) out[row] = bc;
}

extern "C" void kernel_launch(void* const* d_in, const int* in_sizes, int n_in,
                              void* d_out, int out_size, void* d_ws, size_t ws_size,
                              hipStream_t stream) {
    const float* h  = (const float*)d_in[0];
    const float* cb = (const float*)d_in[1];
    int* out = (int*)d_out;

    unsigned char* ws = (unsigned char*)d_ws;
    unsigned short* cbb = (unsigned short*)ws;                 // 1 MB
    float* csq = (float*)(ws + 1048576);                       // 2 KB
    uint4* slots = (uint4*)(ws + 1048576 + 2048);              // 2 MB (65536*2*16B)

    const int nrows = in_sizes[0] / D_DIM;                     // 65536

    prep_kernel<<<dim3(K_CB), dim3(256), 0, stream>>>(cb, cbb, csq);
    coarse_kernel<<<dim3((nrows / BM) * 2), dim3(256), 0, stream>>>(h, cbb, csq, slots);
    refine_kernel<<<dim3(nrows / 4), dim3(256), 0, stream>>>(h, cb, csq, slots, out);
}